// Round 4
// baseline (336.615 us; speedup 1.0000x reference)
//
#include <hip/hip_runtime.h>
#include <hip/hip_bf16.h>

#define B_  4
#define C_  256
#define C8_ 32
#define N_  16384

typedef unsigned short ushort_t;
typedef __attribute__((ext_vector_type(8))) short short8;
typedef __attribute__((ext_vector_type(4))) float floatx4;

__device__ __forceinline__ short bf16_rne(float f) {
  unsigned u = __float_as_uint(f);
  u += 0x7fffu + ((u >> 16) & 1u);
  return (short)(u >> 16);
}

// K0: zero den; cast Wk -> bf16. grid 32 x 256.
__global__ __launch_bounds__(256) void k0_init(const float* __restrict__ Wk,
                                               ushort_t* __restrict__ Wkb,
                                               float* __restrict__ den) {
  const int i = blockIdx.x * 256 + threadIdx.x;
  Wkb[i] = (ushort_t)bf16_rne(Wk[i]);
  if (i < 128) den[i] = 0.f;
}

// KT: x[b][c][n] fp32 -> xT[b][n][c] bf16, 64x64 LDS tiles. grid 4096.
__global__ __launch_bounds__(256) void kT_transpose(const float* __restrict__ x,
                                                    ushort_t* __restrict__ xT) {
  __shared__ ushort_t T[64 * 70];
  const int t = threadIdx.x;
  const int b = blockIdx.x >> 10;
  const int c0 = ((blockIdx.x >> 8) & 3) * 64;
  const int n0 = (blockIdx.x & 255) * 64;
  const int r = t >> 2, q = t & 3;
  const float* xp = x + (size_t)(b * C_ + c0 + r) * N_ + n0 + q * 16;
  unsigned* Tw = (unsigned*)&T[r * 70 + q * 16];
#pragma unroll
  for (int i = 0; i < 4; ++i) {
    float4 v = *(const float4*)(xp + i * 4);
    __hip_bfloat162 h0 = __float22bfloat162_rn(make_float2(v.x, v.y));
    __hip_bfloat162 h1 = __float22bfloat162_rn(make_float2(v.z, v.w));
    Tw[i * 2 + 0] = *(unsigned*)&h0;
    Tw[i * 2 + 1] = *(unsigned*)&h1;
  }
  __syncthreads();
  const int n = t >> 2;
  unsigned u[8];
#pragma unroll
  for (int j = 0; j < 8; ++j) {
    unsigned lo = T[(q * 16 + 2 * j) * 70 + n];
    unsigned hi = T[(q * 16 + 2 * j + 1) * 70 + n];
    u[j] = lo | (hi << 16);
  }
  ushort_t* dst = xT + (size_t)(b * N_ + n0 + n) * C_ + c0 + q * 16;
  *(uint4*)(dst) = make_uint4(u[0], u[1], u[2], u[3]);
  *(uint4*)(dst + 8) = make_uint4(u[4], u[5], u[6], u[7]);
}

// K1: p = exp(Wk.x + bk), den += rowsum(p). grid 1024 = B*256 (64n chunks), 4 waves.
__global__ __launch_bounds__(256) void k1_p(const ushort_t* __restrict__ xT,
                                            const ushort_t* __restrict__ Wkb,
                                            const float* __restrict__ bk,
                                            ushort_t* __restrict__ p,
                                            float* __restrict__ den) {
  const int t = threadIdx.x;
  const int lane = t & 63;
  const int w = t >> 6;
  const int b = blockIdx.x >> 8;
  const int n0 = (blockIdx.x & 255) * 64 + w * 16;
  const int l15 = lane & 15, l4 = lane >> 4;
  const floatx4 z = {0.f, 0.f, 0.f, 0.f};
  floatx4 acc[2];
  acc[0] = z; acc[1] = z;
  short8 bfr[8];
#pragma unroll
  for (int kc = 0; kc < 8; ++kc)
    bfr[kc] = *(const short8*)&xT[(size_t)(b * N_ + n0 + l15) * C_ + kc * 32 + l4 * 8];
#pragma unroll
  for (int kc = 0; kc < 8; ++kc) {
    short8 a0 = *(const short8*)&Wkb[l15 * C_ + kc * 32 + l4 * 8];
    short8 a1 = *(const short8*)&Wkb[(16 + l15) * C_ + kc * 32 + l4 * 8];
    acc[0] = __builtin_amdgcn_mfma_f32_16x16x32_bf16(a0, bfr[kc], acc[0], 0, 0, 0);
    acc[1] = __builtin_amdgcn_mfma_f32_16x16x32_bf16(a1, bfr[kc], acc[1], 0, 0, 0);
  }
#pragma unroll
  for (int mt = 0; mt < 2; ++mt) {
#pragma unroll
    for (int rg = 0; rg < 4; ++rg) {
      const int o = mt * 16 + l4 * 4 + rg;
      const int n = n0 + l15;
      float pe = __expf(acc[mt][rg] + bk[o]);
      p[(size_t)(b * C8_ + o) * N_ + n] = (ushort_t)bf16_rne(pe);
      float s = pe;
      s += __shfl_xor(s, 1); s += __shfl_xor(s, 2);
      s += __shfl_xor(s, 4); s += __shfl_xor(s, 8);
      if (l15 == 0) atomicAdd(&den[b * C8_ + o], s);
    }
  }
}

// K3: kxp[b][ch][o][c] = sum_{n in 128-chunk} p[o][n]*x[c][n].
// x staged fp32->bf16 into swizzled LDS (dense 1KB loads); A=p prefetched.
// grid 512 = B*128, block 4 waves; wave = 32o x 64c (4 c-tiles).
__global__ __launch_bounds__(256) void k3_kxp(const float* __restrict__ x,
                                              const ushort_t* __restrict__ p,
                                              float* __restrict__ kxp) {
  __shared__ uint4 XB[4096];  // 256 c-rows x 16 chunks of 16B (128n bf16), XOR-swizzled
  const int t = threadIdx.x;
  const int lane = t & 63;
  const int w = t >> 6;
  const int b = blockIdx.x >> 7;
  const int chn = blockIdx.x & 127;
  const int n0 = chn * 128;
  const int l15 = lane & 15, l4 = lane >> 4;

  short8 a[2][4];
#pragma unroll
  for (int ot = 0; ot < 2; ++ot)
#pragma unroll
    for (int kc = 0; kc < 4; ++kc)
      a[ot][kc] = *(const short8*)&p[(size_t)(b * C8_ + ot * 16 + l15) * N_ + n0 + kc * 32 + l4 * 8];

#pragma unroll
  for (int s = 0; s < 32; ++s) {
    const int f = (w * 32 + s) * 1024 + lane * 16;
    const int i = f >> 9, rb = f & 511;
    float4 v = *(const float4*)(x + (size_t)(b * C_ + i) * N_ + n0 + (rb >> 2));
    __hip_bfloat162 h0 = __float22bfloat162_rn(make_float2(v.x, v.y));
    __hip_bfloat162 h1 = __float22bfloat162_rn(make_float2(v.z, v.w));
    const int j = rb >> 5, hf = (rb >> 4) & 1;
    unsigned* dst = (unsigned*)((char*)XB + i * 256 + ((j ^ (i & 15)) << 4) + hf * 8);
    dst[0] = *(unsigned*)&h0;
    dst[1] = *(unsigned*)&h1;
  }
  __syncthreads();

  const floatx4 z = {0.f, 0.f, 0.f, 0.f};
  floatx4 acc[2][4];
#pragma unroll
  for (int ot = 0; ot < 2; ++ot)
#pragma unroll
    for (int q = 0; q < 4; ++q) acc[ot][q] = z;

#pragma unroll
  for (int kc = 0; kc < 4; ++kc) {
    const int jj = kc * 4 + l4;
#pragma unroll
    for (int q = 0; q < 4; ++q) {
      const int i = (w * 4 + q) * 16 + l15;
      short8 bf = *(const short8*)((char*)XB + i * 256 + ((jj ^ (i & 15)) << 4));
      acc[0][q] = __builtin_amdgcn_mfma_f32_16x16x32_bf16(a[0][kc], bf, acc[0][q], 0, 0, 0);
      acc[1][q] = __builtin_amdgcn_mfma_f32_16x16x32_bf16(a[1][kc], bf, acc[1][q], 0, 0, 0);
    }
  }
  float* dst = kxp + (size_t)(b * 128 + chn) * (C8_ * C_);
#pragma unroll
  for (int ot = 0; ot < 2; ++ot)
#pragma unroll
    for (int q = 0; q < 4; ++q)
#pragma unroll
      for (int rg = 0; rg < 4; ++rg) {
        const int o = ot * 16 + l4 * 4 + rg;
        const int c = (w * 4 + q) * 16 + l15;
        dst[o * C_ + c] = acc[ot][q][rg];
      }
}

// K3b: kx[b][o][c] = (sum_ch kxp)/den. grid 128 = B*32(o), block 256(c).
__global__ __launch_bounds__(256) void k3b_reduce(const float* __restrict__ kxp,
                                                  const float* __restrict__ den,
                                                  float* __restrict__ kx) {
  const int t = threadIdx.x;
  const int b = blockIdx.x >> 5;
  const int o = blockIdx.x & 31;
  float s = 0.f;
  for (int ch = 0; ch < 128; ++ch)
    s += kxp[(size_t)(b * 128 + ch) * (C8_ * C_) + o * C_ + t];
  kx[(size_t)(b * C8_ + o) * C_ + t] = s / den[b * C8_ + o];
}

// K4a: kv[b][o][c] = Wv[c][:].kx[b][o][:] + bv[c]. grid 128, thread = c.
__global__ __launch_bounds__(256) void k4a_kv(const float* __restrict__ Wv,
                                              const float* __restrict__ bv,
                                              const float* __restrict__ kx,
                                              float* __restrict__ kv) {
  __shared__ float kxl[C_];
  const int t = threadIdx.x;
  const int bo = blockIdx.x;
  kxl[t] = kx[(size_t)bo * C_ + t];
  __syncthreads();
  const float4* wr = (const float4*)&Wv[(size_t)t * C_];
  float s = 0.f;
#pragma unroll 8
  for (int c4 = 0; c4 < 64; ++c4) {
    float4 wv = wr[c4];
    float4 k4 = *(const float4*)&kxl[c4 * 4];
    s += wv.x * k4.x + wv.y * k4.y + wv.z * k4.z + wv.w * k4.w;
  }
  kv[(size_t)bo * C_ + t] = s + bv[t];
}

// K4b: Mt[b][c][c''] bf16 (rows = out-channel c, K5's B operand); r[b][c]. grid 64.
__global__ __launch_bounds__(256) void k4b_M(const float* __restrict__ Wq,
                                             const float* __restrict__ bq,
                                             const float* __restrict__ kv,
                                             ushort_t* __restrict__ Mt,
                                             float* __restrict__ r) {
  __shared__ float kvl[C8_ * C_];
  __shared__ float wqT[16 * C8_];
  const int t = threadIdx.x;
  const int b = blockIdx.x >> 4;
  const int c0 = (blockIdx.x & 15) * 16;
  for (int s = 0; s < 32; ++s)
    kvl[s * 256 + t] = kv[(size_t)b * C8_ * C_ + s * 256 + t];
#pragma unroll
  for (int s = 0; s < 2; ++s) {
    int f = s * 256 + t;
    int o = f >> 4, i = f & 15;
    wqT[i * C8_ + o] = Wq[o * C_ + c0 + i];
  }
  __syncthreads();
  float kvreg[C8_];
#pragma unroll
  for (int o = 0; o < C8_; ++o) kvreg[o] = kvl[o * C_ + t];
  for (int i = 0; i < 16; ++i) {
    const float4* w4 = (const float4*)&wqT[i * C8_];
    float s = 0.f;
#pragma unroll
    for (int o8 = 0; o8 < 8; ++o8) {
      float4 wv = w4[o8];
      s += wv.x * kvreg[o8 * 4] + wv.y * kvreg[o8 * 4 + 1] +
           wv.z * kvreg[o8 * 4 + 2] + wv.w * kvreg[o8 * 4 + 3];
    }
    Mt[(size_t)(b * C_ + t) * C_ + c0 + i] = (ushort_t)bf16_rne(s);
  }
  if (c0 == 0) {
    float rr = 0.f;
#pragma unroll
    for (int o = 0; o < C8_; ++o) rr += bq[o] * kvreg[o];
    r[b * C_ + t] = rr;
  }
}

// K5: out = gamma*(x^T.M + r) + x_flat. Mt c-half staged dense into swizzled LDS;
// A/resid/r prefetched. grid 2048 = B*256(nt)*2(c-half), block 4 waves = 64n x 128c.
__global__ __launch_bounds__(256) void k5_mfma(const float* __restrict__ x,
                                               const ushort_t* __restrict__ xT,
                                               const ushort_t* __restrict__ Mt,
                                               const float* __restrict__ r,
                                               const float* __restrict__ gamma_p,
                                               float* __restrict__ out) {
  __shared__ uint4 MtL[4096];  // 128 c-rows x 32 chunks of 16B (256k bf16), XOR-swizzled
  const int t = threadIdx.x;
  const int lane = t & 63;
  const int w = t >> 6;
  const int b = blockIdx.x >> 9;
  const int nt = (blockIdx.x >> 1) & 255;
  const int ch = blockIdx.x & 1;
  const int n0 = nt * 64 + w * 16;
  const int c0 = ch * 128;
  const int l15 = lane & 15, l4 = lane >> 4;

  // prefetch r, residual, A-frags (latency hides under staging + barrier)
  float rr[8];
#pragma unroll
  for (int ct = 0; ct < 8; ++ct) rr[ct] = r[b * C_ + c0 + ct * 16 + l15];
  float rv[8][4];
#pragma unroll
  for (int ct = 0; ct < 8; ++ct)
#pragma unroll
    for (int rg = 0; rg < 4; ++rg)
      rv[ct][rg] = x[((size_t)b * N_ + n0 + l4 * 4 + rg) * C_ + c0 + ct * 16 + l15];
  short8 a[8];
#pragma unroll
  for (int kc = 0; kc < 8; ++kc)
    a[kc] = *(const short8*)&xT[(size_t)(b * N_ + n0 + l15) * C_ + kc * 32 + l4 * 8];

  // stage Mt c-half: 64 KB flat-contiguous, 1 KB per instruction
  const char* Mth = (const char*)(Mt + (size_t)(b * C_ + c0) * C_);
#pragma unroll
  for (int s = 0; s < 16; ++s) {
    const int f = (w * 16 + s) * 1024 + lane * 16;
    const int i = f >> 9, j = (f & 511) >> 4;
    MtL[i * 32 + (j ^ (i & 31))] = *(const uint4*)(Mth + f);
  }
  __syncthreads();

  const floatx4 z = {0.f, 0.f, 0.f, 0.f};
  floatx4 acc[8];
#pragma unroll
  for (int ct = 0; ct < 8; ++ct) acc[ct] = z;
#pragma unroll
  for (int kc = 0; kc < 8; ++kc) {
    const int jj = kc * 4 + l4;
#pragma unroll
    for (int ct = 0; ct < 8; ++ct) {
      const int i = ct * 16 + l15;
      short8 bf = *(const short8*)&MtL[i * 32 + (jj ^ (i & 31))];
      acc[ct] = __builtin_amdgcn_mfma_f32_16x16x32_bf16(a[kc], bf, acc[ct], 0, 0, 0);
    }
  }
  const float g = gamma_p[0];
#pragma unroll
  for (int ct = 0; ct < 8; ++ct) {
    const int c = c0 + ct * 16 + l15;
#pragma unroll
    for (int rg = 0; rg < 4; ++rg) {
      const int n = n0 + l4 * 4 + rg;
      out[((size_t)b * N_ + n) * C_ + c] = g * (acc[ct][rg] + rr[ct]) + rv[ct][rg];
    }
  }
}

extern "C" void kernel_launch(void* const* d_in, const int* in_sizes, int n_in,
                              void* d_out, int out_size, void* d_ws, size_t ws_size,
                              hipStream_t stream) {
  const float* x  = (const float*)d_in[0];
  const float* Wq = (const float*)d_in[1];
  const float* bq = (const float*)d_in[2];
  const float* Wk = (const float*)d_in[3];
  const float* bk = (const float*)d_in[4];
  const float* Wv = (const float*)d_in[5];
  const float* bv = (const float*)d_in[6];
  const float* gm = (const float*)d_in[7];
  float* out = (float*)d_out;

  float* ws = (float*)d_ws;
  float*    den = ws;                                    // 128
  ushort_t* Wkb = (ushort_t*)(ws + 128);                 // 4096 fl
  ushort_t* xT  = (ushort_t*)(ws + 128 + 4096);          // 8388608 fl
  ushort_t* p   = (ushort_t*)(ws + 128 + 4096 + 8388608);            // 1048576 fl
  float*    kxp = ws + 128 + 4096 + 8388608 + 1048576;               // 4194304 fl
  float*    kx  = kxp + 4194304;                         // 32768
  float*    kv  = kx + 32768;                            // 32768
  ushort_t* Mt  = (ushort_t*)(kv + 32768);               // 131072 fl
  float*    r   = (float*)(kv + 32768 + 131072);         // 1024

  k0_init     <<<32,   256, 0, stream>>>(Wk, Wkb, den);
  kT_transpose<<<4096, 256, 0, stream>>>(x, xT);
  k1_p        <<<1024, 256, 0, stream>>>(xT, Wkb, bk, p, den);
  k3_kxp      <<<512,  256, 0, stream>>>(x, p, kxp);
  k3b_reduce  <<<128,  256, 0, stream>>>(kxp, den, kx);
  k4a_kv      <<<128,  256, 0, stream>>>(Wv, bv, kx, kv);
  k4b_M       <<<64,   256, 0, stream>>>(Wq, bq, kv, Mt, r);
  k5_mfma     <<<2048, 256, 0, stream>>>(x, xT, Mt, r, gm, out);
}

// Round 5
// 205.563 us; speedup vs baseline: 1.6375x; 1.6375x over previous
//
#include <hip/hip_runtime.h>
#include <hip/hip_bf16.h>

#define B_  4
#define C_  256
#define C8_ 32
#define N_  16384

typedef unsigned short ushort_t;
typedef __attribute__((ext_vector_type(8))) short short8;
typedef __attribute__((ext_vector_type(4))) float floatx4;

__device__ __forceinline__ short bf16_rne(float f) {
  unsigned u = __float_as_uint(f);
  u += 0x7fffu + ((u >> 16) & 1u);
  return (short)(u >> 16);
}

// K0: cast Wk -> bf16. grid 32 x 256.
__global__ __launch_bounds__(256) void k0_init(const float* __restrict__ Wk,
                                               ushort_t* __restrict__ Wkb) {
  const int i = blockIdx.x * 256 + threadIdx.x;
  Wkb[i] = (ushort_t)bf16_rne(Wk[i]);
}

// KT: x[b][c][n] fp32 -> xT[b][n][c] bf16, 64x64 LDS tiles. grid 4096.
__global__ __launch_bounds__(256) void kT_transpose(const float* __restrict__ x,
                                                    ushort_t* __restrict__ xT) {
  __shared__ ushort_t T[64 * 70];
  const int t = threadIdx.x;
  const int b = blockIdx.x >> 10;
  const int c0 = ((blockIdx.x >> 8) & 3) * 64;
  const int n0 = (blockIdx.x & 255) * 64;
  const int r = t >> 2, q = t & 3;
  const float* xp = x + (size_t)(b * C_ + c0 + r) * N_ + n0 + q * 16;
  unsigned* Tw = (unsigned*)&T[r * 70 + q * 16];
#pragma unroll
  for (int i = 0; i < 4; ++i) {
    float4 v = *(const float4*)(xp + i * 4);
    __hip_bfloat162 h0 = __float22bfloat162_rn(make_float2(v.x, v.y));
    __hip_bfloat162 h1 = __float22bfloat162_rn(make_float2(v.z, v.w));
    Tw[i * 2 + 0] = *(unsigned*)&h0;
    Tw[i * 2 + 1] = *(unsigned*)&h1;
  }
  __syncthreads();
  const int n = t >> 2;
  unsigned u[8];
#pragma unroll
  for (int j = 0; j < 8; ++j) {
    unsigned lo = T[(q * 16 + 2 * j) * 70 + n];
    unsigned hi = T[(q * 16 + 2 * j + 1) * 70 + n];
    u[j] = lo | (hi << 16);
  }
  ushort_t* dst = xT + (size_t)(b * N_ + n0 + n) * C_ + c0 + q * 16;
  *(uint4*)(dst) = make_uint4(u[0], u[1], u[2], u[3]);
  *(uint4*)(dst + 8) = make_uint4(u[4], u[5], u[6], u[7]);
}

// K1: p = exp(Wk.x + bk); per-wave den partials -> denp (NO atomics).
// grid 1024 = B*256 (64n chunks), 4 waves; wave = 32o x 16n.
__global__ __launch_bounds__(256) void k1_p(const ushort_t* __restrict__ xT,
                                            const ushort_t* __restrict__ Wkb,
                                            const float* __restrict__ bk,
                                            ushort_t* __restrict__ p,
                                            float* __restrict__ denp) {
  const int t = threadIdx.x;
  const int lane = t & 63;
  const int w = t >> 6;
  const int b = blockIdx.x >> 8;
  const int n0 = (blockIdx.x & 255) * 64 + w * 16;
  const int l15 = lane & 15, l4 = lane >> 4;
  const floatx4 z = {0.f, 0.f, 0.f, 0.f};
  floatx4 acc[2];
  acc[0] = z; acc[1] = z;
  short8 bfr[8];
#pragma unroll
  for (int kc = 0; kc < 8; ++kc)
    bfr[kc] = *(const short8*)&xT[(size_t)(b * N_ + n0 + l15) * C_ + kc * 32 + l4 * 8];
#pragma unroll
  for (int kc = 0; kc < 8; ++kc) {
    short8 a0 = *(const short8*)&Wkb[l15 * C_ + kc * 32 + l4 * 8];
    short8 a1 = *(const short8*)&Wkb[(16 + l15) * C_ + kc * 32 + l4 * 8];
    acc[0] = __builtin_amdgcn_mfma_f32_16x16x32_bf16(a0, bfr[kc], acc[0], 0, 0, 0);
    acc[1] = __builtin_amdgcn_mfma_f32_16x16x32_bf16(a1, bfr[kc], acc[1], 0, 0, 0);
  }
  float* dwp = denp + ((size_t)blockIdx.x * 4 + w) * C8_;
#pragma unroll
  for (int mt = 0; mt < 2; ++mt) {
#pragma unroll
    for (int rg = 0; rg < 4; ++rg) {
      const int o = mt * 16 + l4 * 4 + rg;
      const int n = n0 + l15;
      float pe = __expf(acc[mt][rg] + bk[o]);
      p[(size_t)(b * C8_ + o) * N_ + n] = (ushort_t)bf16_rne(pe);
      float s = pe;
      s += __shfl_xor(s, 1); s += __shfl_xor(s, 2);
      s += __shfl_xor(s, 4); s += __shfl_xor(s, 8);
      if (l15 == 0) dwp[o] = s;
    }
  }
}

// K3: kxp[b][ch][o][c] = sum_{n in 128-chunk} p[o][n]*x[c][n].
// x staged fp32->bf16 into swizzled LDS (dense 1KB loads); A=p prefetched.
// grid 512 = B*128, block 4 waves; wave = 32o x 64c (4 c-tiles).
__global__ __launch_bounds__(256) void k3_kxp(const float* __restrict__ x,
                                              const ushort_t* __restrict__ p,
                                              float* __restrict__ kxp) {
  __shared__ uint4 XB[4096];  // 256 c-rows x 16 chunks of 16B (128n bf16), XOR-swizzled
  const int t = threadIdx.x;
  const int lane = t & 63;
  const int w = t >> 6;
  const int b = blockIdx.x >> 7;
  const int chn = blockIdx.x & 127;
  const int n0 = chn * 128;
  const int l15 = lane & 15, l4 = lane >> 4;

  short8 a[2][4];
#pragma unroll
  for (int ot = 0; ot < 2; ++ot)
#pragma unroll
    for (int kc = 0; kc < 4; ++kc)
      a[ot][kc] = *(const short8*)&p[(size_t)(b * C8_ + ot * 16 + l15) * N_ + n0 + kc * 32 + l4 * 8];

#pragma unroll
  for (int s = 0; s < 32; ++s) {
    const int f = (w * 32 + s) * 1024 + lane * 16;
    const int i = f >> 9, rb = f & 511;
    float4 v = *(const float4*)(x + (size_t)(b * C_ + i) * N_ + n0 + (rb >> 2));
    __hip_bfloat162 h0 = __float22bfloat162_rn(make_float2(v.x, v.y));
    __hip_bfloat162 h1 = __float22bfloat162_rn(make_float2(v.z, v.w));
    const int j = rb >> 5, hf = (rb >> 4) & 1;
    unsigned* dst = (unsigned*)((char*)XB + i * 256 + ((j ^ (i & 15)) << 4) + hf * 8);
    dst[0] = *(unsigned*)&h0;
    dst[1] = *(unsigned*)&h1;
  }
  __syncthreads();

  const floatx4 z = {0.f, 0.f, 0.f, 0.f};
  floatx4 acc[2][4];
#pragma unroll
  for (int ot = 0; ot < 2; ++ot)
#pragma unroll
    for (int q = 0; q < 4; ++q) acc[ot][q] = z;

#pragma unroll
  for (int kc = 0; kc < 4; ++kc) {
    const int jj = kc * 4 + l4;
#pragma unroll
    for (int q = 0; q < 4; ++q) {
      const int i = (w * 4 + q) * 16 + l15;
      short8 bf = *(const short8*)((char*)XB + i * 256 + ((jj ^ (i & 15)) << 4));
      acc[0][q] = __builtin_amdgcn_mfma_f32_16x16x32_bf16(a[0][kc], bf, acc[0][q], 0, 0, 0);
      acc[1][q] = __builtin_amdgcn_mfma_f32_16x16x32_bf16(a[1][kc], bf, acc[1][q], 0, 0, 0);
    }
  }
  float* dst = kxp + (size_t)(b * 128 + chn) * (C8_ * C_);
#pragma unroll
  for (int ot = 0; ot < 2; ++ot)
#pragma unroll
    for (int q = 0; q < 4; ++q)
#pragma unroll
      for (int rg = 0; rg < 4; ++rg) {
        const int o = ot * 16 + l4 * 4 + rg;
        const int c = (w * 4 + q) * 16 + l15;
        dst[o * C_ + c] = acc[ot][q][rg];
      }
}

// K3b: den[b][o] = sum over 1024 wave-partials; kx[b][o][c] = (sum_ch kxp)/den.
// grid 128 = B*32(o), block 256(c).
__global__ __launch_bounds__(256) void k3b_reduce(const float* __restrict__ kxp,
                                                  const float* __restrict__ denp,
                                                  float* __restrict__ kx) {
  __shared__ float red[256];
  const int t = threadIdx.x;
  const int b = blockIdx.x >> 5;
  const int o = blockIdx.x & 31;
  float ds = 0.f;
#pragma unroll
  for (int k = 0; k < 4; ++k)
    ds += denp[(size_t)(b * 1024 + k * 256 + t) * C8_ + o];
  red[t] = ds;
  __syncthreads();
  for (int st = 128; st > 0; st >>= 1) {
    if (t < st) red[t] += red[t + st];
    __syncthreads();
  }
  const float inv = 1.0f / red[0];
  float s = 0.f;
  for (int ch = 0; ch < 128; ++ch)
    s += kxp[(size_t)(b * 128 + ch) * (C8_ * C_) + o * C_ + t];
  kx[(size_t)(b * C8_ + o) * C_ + t] = s * inv;
}

// K4a: kv[b][o][c] = Wv[c][:].kx[b][o][:] + bv[c]. grid 128, thread = c.
__global__ __launch_bounds__(256) void k4a_kv(const float* __restrict__ Wv,
                                              const float* __restrict__ bv,
                                              const float* __restrict__ kx,
                                              float* __restrict__ kv) {
  __shared__ float kxl[C_];
  const int t = threadIdx.x;
  const int bo = blockIdx.x;
  kxl[t] = kx[(size_t)bo * C_ + t];
  __syncthreads();
  const float4* wr = (const float4*)&Wv[(size_t)t * C_];
  float s = 0.f;
#pragma unroll 8
  for (int c4 = 0; c4 < 64; ++c4) {
    float4 wv = wr[c4];
    float4 k4 = *(const float4*)&kxl[c4 * 4];
    s += wv.x * k4.x + wv.y * k4.y + wv.z * k4.z + wv.w * k4.w;
  }
  kv[(size_t)bo * C_ + t] = s + bv[t];
}

// K4b: Mt[b][c][c''] bf16 (rows = out-channel c, K5's B operand); r[b][c]. grid 64.
__global__ __launch_bounds__(256) void k4b_M(const float* __restrict__ Wq,
                                             const float* __restrict__ bq,
                                             const float* __restrict__ kv,
                                             ushort_t* __restrict__ Mt,
                                             float* __restrict__ r) {
  __shared__ float kvl[C8_ * C_];
  __shared__ float wqT[16 * C8_];
  const int t = threadIdx.x;
  const int b = blockIdx.x >> 4;
  const int c0 = (blockIdx.x & 15) * 16;
  for (int s = 0; s < 32; ++s)
    kvl[s * 256 + t] = kv[(size_t)b * C8_ * C_ + s * 256 + t];
#pragma unroll
  for (int s = 0; s < 2; ++s) {
    int f = s * 256 + t;
    int o = f >> 4, i = f & 15;
    wqT[i * C8_ + o] = Wq[o * C_ + c0 + i];
  }
  __syncthreads();
  float kvreg[C8_];
#pragma unroll
  for (int o = 0; o < C8_; ++o) kvreg[o] = kvl[o * C_ + t];
  for (int i = 0; i < 16; ++i) {
    const float4* w4 = (const float4*)&wqT[i * C8_];
    float s = 0.f;
#pragma unroll
    for (int o8 = 0; o8 < 8; ++o8) {
      float4 wv = w4[o8];
      s += wv.x * kvreg[o8 * 4] + wv.y * kvreg[o8 * 4 + 1] +
           wv.z * kvreg[o8 * 4 + 2] + wv.w * kvreg[o8 * 4 + 3];
    }
    Mt[(size_t)(b * C_ + t) * C_ + c0 + i] = (ushort_t)bf16_rne(s);
  }
  if (c0 == 0) {
    float rr = 0.f;
#pragma unroll
    for (int o = 0; o < C8_; ++o) rr += bq[o] * kvreg[o];
    r[b * C_ + t] = rr;
  }
}

// K5: out = gamma*(x^T.M + r) + x_flat. Mt c-half staged dense into swizzled LDS;
// A/resid/r prefetched. grid 2048 = B*256(nt)*2(c-half), block 4 waves = 64n x 128c.
__global__ __launch_bounds__(256) void k5_mfma(const float* __restrict__ x,
                                               const ushort_t* __restrict__ xT,
                                               const ushort_t* __restrict__ Mt,
                                               const float* __restrict__ r,
                                               const float* __restrict__ gamma_p,
                                               float* __restrict__ out) {
  __shared__ uint4 MtL[4096];  // 128 c-rows x 32 chunks of 16B, XOR-swizzled
  const int t = threadIdx.x;
  const int lane = t & 63;
  const int w = t >> 6;
  const int b = blockIdx.x >> 9;
  const int nt = (blockIdx.x >> 1) & 255;
  const int ch = blockIdx.x & 1;
  const int n0 = nt * 64 + w * 16;
  const int c0 = ch * 128;
  const int l15 = lane & 15, l4 = lane >> 4;

  float rr[8];
#pragma unroll
  for (int ct = 0; ct < 8; ++ct) rr[ct] = r[b * C_ + c0 + ct * 16 + l15];
  float rv[8][4];
#pragma unroll
  for (int ct = 0; ct < 8; ++ct)
#pragma unroll
    for (int rg = 0; rg < 4; ++rg)
      rv[ct][rg] = x[((size_t)b * N_ + n0 + l4 * 4 + rg) * C_ + c0 + ct * 16 + l15];
  short8 a[8];
#pragma unroll
  for (int kc = 0; kc < 8; ++kc)
    a[kc] = *(const short8*)&xT[(size_t)(b * N_ + n0 + l15) * C_ + kc * 32 + l4 * 8];

  const char* Mth = (const char*)(Mt + (size_t)(b * C_ + c0) * C_);
#pragma unroll
  for (int s = 0; s < 16; ++s) {
    const int f = (w * 16 + s) * 1024 + lane * 16;
    const int i = f >> 9, j = (f & 511) >> 4;
    MtL[i * 32 + (j ^ (i & 31))] = *(const uint4*)(Mth + f);
  }
  __syncthreads();

  const floatx4 z = {0.f, 0.f, 0.f, 0.f};
  floatx4 acc[8];
#pragma unroll
  for (int ct = 0; ct < 8; ++ct) acc[ct] = z;
#pragma unroll
  for (int kc = 0; kc < 8; ++kc) {
    const int jj = kc * 4 + l4;
#pragma unroll
    for (int ct = 0; ct < 8; ++ct) {
      const int i = ct * 16 + l15;
      short8 bf = *(const short8*)&MtL[i * 32 + (jj ^ (i & 31))];
      acc[ct] = __builtin_amdgcn_mfma_f32_16x16x32_bf16(a[kc], bf, acc[ct], 0, 0, 0);
    }
  }
  const float g = gamma_p[0];
#pragma unroll
  for (int ct = 0; ct < 8; ++ct) {
    const int c = c0 + ct * 16 + l15;
#pragma unroll
    for (int rg = 0; rg < 4; ++rg) {
      const int n = n0 + l4 * 4 + rg;
      out[((size_t)b * N_ + n) * C_ + c] = g * (acc[ct][rg] + rr[ct]) + rv[ct][rg];
    }
  }
}

extern "C" void kernel_launch(void* const* d_in, const int* in_sizes, int n_in,
                              void* d_out, int out_size, void* d_ws, size_t ws_size,
                              hipStream_t stream) {
  const float* x  = (const float*)d_in[0];
  const float* Wq = (const float*)d_in[1];
  const float* bq = (const float*)d_in[2];
  const float* Wk = (const float*)d_in[3];
  const float* bk = (const float*)d_in[4];
  const float* Wv = (const float*)d_in[5];
  const float* bv = (const float*)d_in[6];
  const float* gm = (const float*)d_in[7];
  float* out = (float*)d_out;

  float* ws = (float*)d_ws;
  ushort_t* Wkb  = (ushort_t*)ws;                        // 4096 fl
  ushort_t* xT   = (ushort_t*)(ws + 4096);               // 8388608 fl
  ushort_t* p    = (ushort_t*)(ws + 4096 + 8388608);     // 1048576 fl
  float*    denp = ws + 4096 + 8388608 + 1048576;        // 1024*4*32 = 131072 fl
  float*    kxp  = denp + 131072;                        // 4194304 fl
  float*    kx   = kxp + 4194304;                        // 32768
  float*    kv   = kx + 32768;                           // 32768
  ushort_t* Mt   = (ushort_t*)(kv + 32768);              // 131072 fl
  float*    r    = (float*)(kv + 32768 + 131072);        // 1024

  k0_init     <<<32,   256, 0, stream>>>(Wk, Wkb);
  kT_transpose<<<4096, 256, 0, stream>>>(x, xT);
  k1_p        <<<1024, 256, 0, stream>>>(xT, Wkb, bk, p, denp);
  k3_kxp      <<<512,  256, 0, stream>>>(x, p, kxp);
  k3b_reduce  <<<128,  256, 0, stream>>>(kxp, denp, kx);
  k4a_kv      <<<128,  256, 0, stream>>>(Wv, bv, kx, kv);
  k4b_M       <<<64,   256, 0, stream>>>(Wq, bq, kv, Mt, r);
  k5_mfma     <<<2048, 256, 0, stream>>>(x, xT, Mt, r, gm, out);
}